// Round 6
// baseline (856.373 us; speedup 1.0000x reference)
//
#include <hip/hip_runtime.h>
#include <hip/hip_bf16.h>

// CrystalHypergraphConv — MI355X implementation.
//
// Decomposition: z[e] = A[idx0[e]] + C[idx1[e]] where
//   A = h @ (lin_w[0:128]+lin_w[256:384]) + lin_b   [N,256]
//   C = connect_feats @ lin_w[128:256]              [NHE,256]
// C stored bf16-packed; lane l owns channels {2l,2l+1,128+2l,129+2l} ->
// per-edge gather = one uint2 (C) per lane.
//
// R5 -> R6: k_stats was cache-traffic-bound (1.23GB/pass ~ 7.8TB/s; occ fix
// 41->74% did NOT help). Rewritten with run-amortized A: waves walk contiguous
// CSR-sorted edge chunks, A row loaded once per node-run (deg~16), flush
// sm += k*a + Sc, s2 += a*(k*a + 2*Sc) per run. Per-edge traffic 1536B->520B.
// gemm_rows: LDS transposed xs[k][r] -> 4x broadcast ds_read_b128 per k-iter
// instead of 16x ds_read_b32.

#define EPS_BN 1e-5f

__device__ __forceinline__ float softplus_fast(float x) {
    return fmaxf(x, 0.f) + __logf(1.f + __expf(-fabsf(x)));
}

__device__ __forceinline__ unsigned short f2bf(float f) {
    unsigned u = __float_as_uint(f);
    unsigned r = (u + 0x7fffu + ((u >> 16) & 1u)) >> 16;   // RNE
    return (unsigned short)r;
}
__device__ __forceinline__ float bflo(unsigned u) { return __uint_as_float(u << 16); }
__device__ __forceinline__ float bfhi(unsigned u) { return __uint_as_float(u & 0xffff0000u); }

// packed channel permutation for NCOL=256
__device__ __forceinline__ int perm256(int j) {
    return (j < 128) ? ((j >> 1) * 4 + (j & 1)) : (((j - 128) >> 1) * 4 + 2 + (j & 1));
}

// ---------------- dense GEMM: out[M,NCOL] = in[M,K] @ W[K,NCOL] + bias ----------------
// LDS layout transposed: xs[k*ROWS + r] -> per k-iter ROWS/4 broadcast ds_read_b128.
// OMODE: 0 = natural f32, 1 = packed f32 (A), 2 = packed bf16 (C)
template<int K, int NCOL, int ROWS, int OMODE>
__global__ __launch_bounds__(NCOL) void gemm_rows(
    const float* __restrict__ in, const float* __restrict__ W,
    const float* __restrict__ bias, void* __restrict__ outv, int M)
{
    __shared__ float xs[ROWS * K];
    const int j = threadIdx.x;
    const int r0 = blockIdx.x * ROWS;
    for (int i = j; i < ROWS * K; i += NCOL) {
        int r = i / K;
        int kk = i - r * K;
        int gi = r0 + r;
        xs[kk * ROWS + r] = (gi < M) ? in[(size_t)gi * K + kk] : 0.f;
    }
    __syncthreads();
    float b = bias ? bias[j] : 0.f;
    float acc[ROWS];
#pragma unroll
    for (int r = 0; r < ROWS; r++) acc[r] = b;
    const float4* xs4 = (const float4*)xs;
    for (int k = 0; k < K; k++) {
        float w = W[(size_t)k * NCOL + j];
#pragma unroll
        for (int q = 0; q < ROWS / 4; q++) {
            float4 xv = xs4[k * (ROWS / 4) + q];
            acc[q * 4 + 0] = fmaf(xv.x, w, acc[q * 4 + 0]);
            acc[q * 4 + 1] = fmaf(xv.y, w, acc[q * 4 + 1]);
            acc[q * 4 + 2] = fmaf(xv.z, w, acc[q * 4 + 2]);
            acc[q * 4 + 3] = fmaf(xv.w, w, acc[q * 4 + 3]);
        }
    }
    const int pj = (OMODE && NCOL == 256) ? perm256(j) : j;
#pragma unroll
    for (int r = 0; r < ROWS; r++) {
        int gi = r0 + r;
        if (gi < M) {
            if (OMODE == 2) ((unsigned short*)outv)[(size_t)gi * NCOL + pj] = f2bf(acc[r]);
            else            ((float*)outv)[(size_t)gi * NCOL + pj] = acc[r];
        }
    }
}

// WA[k][j] = lin_w[k][j] + lin_w[k+256][j]
__global__ __launch_bounds__(256) void k_wa(const float* __restrict__ lw, float* __restrict__ WA) {
    int i = blockIdx.x * 256 + threadIdx.x;   // 0..32767
    WA[i] = lw[i] + lw[i + 256 * 256];
}

// ---------------- edge CSR build ----------------
__global__ __launch_bounds__(256) void k_hist(const int* __restrict__ idx0, int* __restrict__ hist, int E) {
    int e = blockIdx.x * 256 + threadIdx.x;
    if (e < E) atomicAdd(&hist[idx0[e]], 1);
}

__global__ __launch_bounds__(256) void k_scan1(const int* __restrict__ hist, int* __restrict__ incl,
                                               int* __restrict__ bsum, int N) {
    __shared__ int s[256];
    int i = blockIdx.x * 256 + threadIdx.x;
    int v = (i < N) ? hist[i] : 0;
    s[threadIdx.x] = v;
    __syncthreads();
    for (int ofs = 1; ofs < 256; ofs <<= 1) {
        int t = (threadIdx.x >= ofs) ? s[threadIdx.x - ofs] : 0;
        __syncthreads();
        s[threadIdx.x] += t;
        __syncthreads();
    }
    if (i < N) incl[i] = s[threadIdx.x];          // written at rowptr+1
    if (threadIdx.x == 255) bsum[blockIdx.x] = s[255];
}

__global__ __launch_bounds__(256) void k_scan2(const int* __restrict__ bsum, int* __restrict__ bofs, int nb) {
    __shared__ int s[256];
    int v = (threadIdx.x < nb) ? bsum[threadIdx.x] : 0;
    s[threadIdx.x] = v;
    __syncthreads();
    for (int ofs = 1; ofs < 256; ofs <<= 1) {
        int t = (threadIdx.x >= ofs) ? s[threadIdx.x - ofs] : 0;
        __syncthreads();
        s[threadIdx.x] += t;
        __syncthreads();
    }
    if (threadIdx.x < nb) bofs[threadIdx.x] = s[threadIdx.x] - v;  // exclusive
}

__global__ __launch_bounds__(256) void k_scan3(int* __restrict__ rowptr, const int* __restrict__ bofs, int N) {
    int i = blockIdx.x * 256 + threadIdx.x;
    if (i < N) rowptr[i + 1] += bofs[blockIdx.x];
    if (i == 0 && blockIdx.x == 0) rowptr[0] = 0;
}

__global__ __launch_bounds__(256) void k_scatter(const int* __restrict__ idx0, const int* __restrict__ idx1,
                                                 const int* __restrict__ rowptr, int* __restrict__ fill,
                                                 int* __restrict__ snode, int* __restrict__ sidx1, int E) {
    int e = blockIdx.x * 256 + threadIdx.x;
    if (e < E) {
        int n = idx0[e];
        int pos = rowptr[n] + atomicAdd(&fill[n], 1);
        snode[pos] = n;
        sidx1[pos] = idx1[e];
    }
}

// ---------------- graph CSR build (nodes sorted by batch) ----------------
__global__ __launch_bounds__(128) void k_gcount(const int* __restrict__ batch, int* __restrict__ gcount, int N) {
    int n = blockIdx.x * 128 + threadIdx.x;
    if (n < N) atomicAdd(&gcount[batch[n]], 1);
}

__global__ __launch_bounds__(128) void k_gscan(const int* __restrict__ gcount, int* __restrict__ gptr) {
    __shared__ int s[128];
    int t = threadIdx.x;
    s[t] = gcount[t];
    __syncthreads();
    for (int ofs = 1; ofs < 128; ofs <<= 1) {
        int v = (t >= ofs) ? s[t - ofs] : 0;
        __syncthreads();
        s[t] += v;
        __syncthreads();
    }
    gptr[t + 1] = s[t];
    if (t == 0) gptr[0] = 0;
}

__global__ __launch_bounds__(128) void k_gscatter(const int* __restrict__ batch, const int* __restrict__ gptr,
                                                  int* __restrict__ gfill, int* __restrict__ gnodes, int N) {
    int n = blockIdx.x * 128 + threadIdx.x;
    if (n < N) {
        int g = batch[n];
        int pos = gptr[g] + atomicAdd(&gfill[g], 1);
        gnodes[pos] = n;
    }
}

// ---------------- BN1 stats: run-amortized A, edge-parallel over contiguous chunks ----------------
// wave (slot) walks contiguous CSR-sorted edges; A row loaded once per node-run.
// per run of k edges: sm += k*a + Sc ; s2 += a*(k*a + 2*Sc); per edge: s2 += c^2.
__global__ __launch_bounds__(256) void k_stats(const float* __restrict__ Apk, const uint2* __restrict__ Cpk,
                                               const int* __restrict__ snode, const int* __restrict__ sidx1,
                                               float* __restrict__ gsum, float* __restrict__ gsq,
                                               int E, int per_slot) {
    __shared__ float4 lsm4[256], lsq4[256];
    const int t = threadIdx.x;
    const int s = t >> 6, l = t & 63;
    const float4* A4 = (const float4*)Apk;
    const long base = (long)(blockIdx.x * 4 + s) * per_slot;
    const int e0 = (int)min((long)E, base);
    const int e1 = (int)min((long)E, base + per_slot);
    float4 sm = {0.f, 0.f, 0.f, 0.f}, s2 = {0.f, 0.f, 0.f, 0.f};
    float4 csr = {0.f, 0.f, 0.f, 0.f};
    float4 a = {0.f, 0.f, 0.f, 0.f};
    int cur_n = -1, runk = 0;
    for (int e = e0; e < e1; e++) {
        int n = snode[e];        // wave-uniform
        int m = sidx1[e];
        if (n != cur_n) {        // wave-uniform branch
            if (runk) {
                float fk = (float)runk;
                sm.x += fmaf(fk, a.x, csr.x);
                sm.y += fmaf(fk, a.y, csr.y);
                sm.z += fmaf(fk, a.z, csr.z);
                sm.w += fmaf(fk, a.w, csr.w);
                float t0 = fmaf(fk, a.x, 2.f * csr.x); s2.x = fmaf(a.x, t0, s2.x);
                float t1 = fmaf(fk, a.y, 2.f * csr.y); s2.y = fmaf(a.y, t1, s2.y);
                float t2 = fmaf(fk, a.z, 2.f * csr.z); s2.z = fmaf(a.z, t2, s2.z);
                float t3 = fmaf(fk, a.w, 2.f * csr.w); s2.w = fmaf(a.w, t3, s2.w);
            }
            a = A4[(size_t)n * 64 + l];
            cur_n = n; runk = 0;
            csr.x = 0.f; csr.y = 0.f; csr.z = 0.f; csr.w = 0.f;
        }
        uint2 p = Cpk[(size_t)m * 64 + l];
        float c0 = bflo(p.x), c1 = bfhi(p.x), c2 = bflo(p.y), c3 = bfhi(p.y);
        csr.x += c0; csr.y += c1; csr.z += c2; csr.w += c3;
        s2.x = fmaf(c0, c0, s2.x);
        s2.y = fmaf(c1, c1, s2.y);
        s2.z = fmaf(c2, c2, s2.z);
        s2.w = fmaf(c3, c3, s2.w);
        runk++;
    }
    if (runk) {
        float fk = (float)runk;
        sm.x += fmaf(fk, a.x, csr.x);
        sm.y += fmaf(fk, a.y, csr.y);
        sm.z += fmaf(fk, a.z, csr.z);
        sm.w += fmaf(fk, a.w, csr.w);
        float t0 = fmaf(fk, a.x, 2.f * csr.x); s2.x = fmaf(a.x, t0, s2.x);
        float t1 = fmaf(fk, a.y, 2.f * csr.y); s2.y = fmaf(a.y, t1, s2.y);
        float t2 = fmaf(fk, a.z, 2.f * csr.z); s2.z = fmaf(a.z, t2, s2.z);
        float t3 = fmaf(fk, a.w, 2.f * csr.w); s2.w = fmaf(a.w, t3, s2.w);
    }
    lsm4[t] = sm;
    lsq4[t] = s2;
    __syncthreads();
    const float* fm = (const float*)lsm4;
    const float* fq = (const float*)lsq4;
    float vs = fm[t] + fm[256 + t] + fm[512 + t] + fm[768 + t];
    float vq = fq[t] + fq[256 + t] + fq[512 + t] + fq[768 + t];
    atomicAdd(&gsum[t], vs);   // packed channel index t
    atomicAdd(&gsq[t], vq);
}

// packed j -> original channel; writes packed scale/shift
__global__ __launch_bounds__(256) void k_bn1fin(const float* __restrict__ sum, const float* __restrict__ sq,
                                                const float* __restrict__ g, const float* __restrict__ b,
                                                float* __restrict__ scale, float* __restrict__ shift, float invE) {
    int j = threadIdx.x;  // packed index
    int l = j >> 2, k = j & 3;
    int ch = (k < 2) ? (2 * l + k) : (128 + 2 * l + (k - 2));
    float mu = sum[j] * invE;
    float var = sq[j] * invE - mu * mu;
    float sc = g[ch] * rsqrtf(var + EPS_BN);
    scale[j] = sc;
    shift[j] = fmaf(-mu, sc, b[ch]);
}

// ---------------- fused msg + segment softmax aggregation (2 waves/block, 1 node/wave) ----------------
__global__ __launch_bounds__(128) void k_aggr(const float* __restrict__ Apk, const uint2* __restrict__ Cpk,
                                              const int* __restrict__ rowptr, const int* __restrict__ sidx1,
                                              const float* __restrict__ scale_pk, const float* __restrict__ shift_pk,
                                              const float* __restrict__ tptr, float* __restrict__ out, int N) {
    const int n = blockIdx.x * 2 + (threadIdx.x >> 6);
    if (n >= N) return;
    const int l = threadIdx.x & 63;
    const float t = tptr[0];
    const float4 sc = ((const float4*)scale_pk)[l];
    const float4 sh = ((const float4*)shift_pk)[l];
    const float4 ap = ((const float4*)Apk)[(size_t)n * 64 + l];
    const float apf0 = fmaf(ap.x, sc.x, sh.x);
    const float apf1 = fmaf(ap.y, sc.y, sh.y);
    const float apc0 = fmaf(ap.z, sc.z, sh.z);
    const float apc1 = fmaf(ap.w, sc.w, sh.w);
    const int e0 = rowptr[n], e1 = rowptr[n + 1];
    float den0 = 0.f, num0 = 0.f, den1 = 0.f, num1 = 0.f;
    // 1-deep software prefetch: gather(e+1) in flight during compute(e)
    uint2 pnext = {0u, 0u};
    if (e0 < e1) pnext = Cpk[(size_t)sidx1[e0] * 64 + l];
    for (int e = e0; e < e1; e++) {
        uint2 p = pnext;
        if (e + 1 < e1) pnext = Cpk[(size_t)sidx1[e + 1] * 64 + l];
        float zf0 = fmaf(bflo(p.x), sc.x, apf0);
        float zf1 = fmaf(bfhi(p.x), sc.y, apf1);
        float zc0 = fmaf(bflo(p.y), sc.z, apc0);
        float zc1 = fmaf(bfhi(p.y), sc.w, apc1);
        float sig0 = __builtin_amdgcn_rcpf(1.f + __expf(-zf0));
        float sig1 = __builtin_amdgcn_rcpf(1.f + __expf(-zf1));
        float msg0 = sig0 * softplus_fast(zc0);
        float msg1 = sig1 * softplus_fast(zc1);
        float p0 = __expf(t * msg0);
        float p1 = __expf(t * msg1);
        den0 += p0; num0 = fmaf(msg0, p0, num0);
        den1 += p1; num1 = fmaf(msg1, p1, num1);
    }
    float2 o;
    o.x = (e1 > e0) ? num0 / den0 : 0.f;
    o.y = (e1 > e0) ? num1 / den1 : 0.f;
    ((float2*)out)[(size_t)n * 64 + l] = o;    // channels 2l, 2l+1 (natural order)
}

// ---------------- BN2 ----------------
__global__ __launch_bounds__(128) void k_bn2stats(const float* __restrict__ out, float* __restrict__ sum,
                                                  float* __restrict__ sq, int N) {
    const int c = threadIdx.x;  // 128
    const int n0 = blockIdx.x * 64;
    const int nend = min(n0 + 64, N);
    float sm = 0.f, s2 = 0.f;
    for (int n = n0; n < nend; n++) {
        float v = out[(size_t)n * 128 + c];
        sm += v;
        s2 = fmaf(v, v, s2);
    }
    atomicAdd(&sum[c], sm);
    atomicAdd(&sq[c], s2);
}

__global__ __launch_bounds__(128) void k_bn2fin(const float* __restrict__ sum, const float* __restrict__ sq,
                                                const float* __restrict__ g, const float* __restrict__ b,
                                                float* __restrict__ scale, float* __restrict__ shift, float invN) {
    int j = threadIdx.x;  // 128
    float mu = sum[j] * invN;
    float var = sq[j] * invN - mu * mu;
    float sc = g[j] * rsqrtf(var + EPS_BN);
    scale[j] = sc;
    shift[j] = fmaf(-mu, sc, b[j]);
}

// ---------------- residual+softplus + mean-pool (batch-CSR, register accum, no LDS) ----------------
template<int SPLIT>
__global__ __launch_bounds__(128) void k_h2pool(const float* __restrict__ out, const float* __restrict__ h,
                                                const int* __restrict__ gptr, const int* __restrict__ gnodes,
                                                const float* __restrict__ scale, const float* __restrict__ shift,
                                                float* __restrict__ pooled) {
    const int g = blockIdx.x & 127;
    const int sp = blockIdx.x >> 7;
    const int c = threadIdx.x;                 // 128
    const float sc = scale[c], sh = shift[c];
    const int i0 = gptr[g], i1 = gptr[g + 1];
    float acc = 0.f;
    for (int i = i0 + sp; i < i1; i += SPLIT) {
        int n = gnodes[i];
        float v = fmaf(out[(size_t)n * 128 + c], sc, sh) + h[(size_t)n * 128 + c];
        acc += softplus_fast(v);
    }
    if (acc != 0.f) atomicAdd(&pooled[g * 128 + c], acc);
}

// ---------------- head ----------------
__global__ __launch_bounds__(256) void k_head(const float* __restrict__ pooled, const int* __restrict__ gcount,
                                              const float* __restrict__ l1w, const float* __restrict__ l1b,
                                              const float* __restrict__ outw, const float* __restrict__ outb,
                                              float* __restrict__ dout) {
    __shared__ float p[128];
    __shared__ float red[256];
    const int g = blockIdx.x;
    const int j = threadIdx.x;  // 256
    if (j < 128) {
        float cnt = (float)max(gcount[g], 1);
        p[j] = pooled[g * 128 + j] / cnt;
    }
    __syncthreads();
    float acc = l1b[j];
    for (int k = 0; k < 128; k++) acc = fmaf(p[k], l1w[k * 256 + j], acc);
    red[j] = softplus_fast(acc) * outw[j];
    __syncthreads();
    for (int s = 128; s > 0; s >>= 1) {
        if (j < s) red[j] += red[j + s];
        __syncthreads();
    }
    if (j == 0) dout[g] = red[0] + outb[0];
}

// ---------------- launch ----------------
extern "C" void kernel_launch(void* const* d_in, const int* in_sizes, int n_in,
                              void* d_out, int out_size, void* d_ws, size_t ws_size,
                              hipStream_t stream) {
    const float* x        = (const float*)d_in[0];
    const float* hedge    = (const float*)d_in[1];
    const int*   iri      = (const int*)d_in[2];
    const int*   batch    = (const int*)d_in[3];
    const float* embed_w  = (const float*)d_in[5];
    const float* embed_b  = (const float*)d_in[6];
    const float* bembed_w = (const float*)d_in[7];
    const float* bembed_b = (const float*)d_in[8];
    const float* lin_w    = (const float*)d_in[9];
    const float* lin_b    = (const float*)d_in[10];
    const float* bn1_g    = (const float*)d_in[11];
    const float* bn1_b    = (const float*)d_in[12];
    const float* bn2_g    = (const float*)d_in[13];
    const float* bn2_b    = (const float*)d_in[14];
    const float* aggr_t   = (const float*)d_in[15];
    const float* l1_w     = (const float*)d_in[16];
    const float* l1_b     = (const float*)d_in[17];
    const float* out_w    = (const float*)d_in[18];
    const float* out_b    = (const float*)d_in[19];

    const int N   = in_sizes[0] / 92;
    const int NHE = in_sizes[1] / 40;
    const int E   = in_sizes[2] / 3;
    const int* idx0 = iri;
    const int* idx1 = iri + E;

    float* ws = (float*)d_ws;
    size_t off = 0;
    auto alloc = [&](size_t elems) -> float* {
        float* p = ws + off;
        off += (elems + 63) & ~(size_t)63;
        return p;
    };
    float* h      = alloc((size_t)N * 128);
    float* cf     = alloc((size_t)NHE * 128);
    float* Apk    = alloc((size_t)N * 256);        // packed f32
    float* Cpk    = alloc((size_t)NHE * 128);      // packed bf16 (NHE*256 u16)
    float* WA     = alloc(128 * 256);
    int*   rowptr = (int*)alloc((size_t)N + 1);
    int*   snode  = (int*)alloc((size_t)E);
    int*   sidx1  = (int*)alloc((size_t)E);
    int*   gptr   = (int*)alloc(129);
    int*   gnodes = (int*)alloc((size_t)N);
    int*   bsum   = (int*)alloc(256);
    int*   bofs   = (int*)alloc(256);
    float* bn1_scale = alloc(256);
    float* bn1_shift = alloc(256);
    float* bn2_scale = alloc(128);
    float* bn2_shift = alloc(128);
    float* outbuf = alloc((size_t)N * 128);
    // contiguous zero region
    float* zbase  = ws + off;
    int*   hist   = (int*)alloc((size_t)N);
    int*   fill   = (int*)alloc((size_t)N);
    int*   gfill  = (int*)alloc(128);
    float* bn1_sum = alloc(256);
    float* bn1_sq  = alloc(256);
    float* bn2_sum = alloc(128);
    float* bn2_sq  = alloc(128);
    float* pooled  = alloc(128 * 128);
    int*   gcount  = (int*)alloc(128);
    size_t zbytes = (size_t)((ws + off) - zbase) * sizeof(float);
    (void)ws_size;  // ~160MB; fit verified R1-R5

    hipMemsetAsync(zbase, 0, zbytes, stream);

    // dense precompute
    gemm_rows<92, 128, 16, 0><<<(N + 15) / 16, 128, 0, stream>>>(x, embed_w, embed_b, h, N);
    gemm_rows<40, 128, 16, 0><<<(NHE + 15) / 16, 128, 0, stream>>>(hedge, bembed_w, bembed_b, cf, NHE);
    k_wa<<<128, 256, 0, stream>>>(lin_w, WA);
    gemm_rows<128, 256, 16, 1><<<(N + 15) / 16, 256, 0, stream>>>(h, WA, lin_b, Apk, N);
    gemm_rows<128, 256, 16, 2><<<(NHE + 15) / 16, 256, 0, stream>>>(cf, lin_w + 128 * 256, nullptr, Cpk, NHE);

    // edge CSR build (counting sort by idx0)
    k_hist<<<(E + 255) / 256, 256, 0, stream>>>(idx0, hist, E);
    int nchunk = (N + 255) / 256;   // 196 <= 256
    k_scan1<<<nchunk, 256, 0, stream>>>(hist, rowptr + 1, bsum, N);
    k_scan2<<<1, 256, 0, stream>>>(bsum, bofs, nchunk);
    k_scan3<<<nchunk, 256, 0, stream>>>(rowptr, bofs, N);
    k_scatter<<<(E + 255) / 256, 256, 0, stream>>>(idx0, idx1, rowptr, fill, snode, sidx1, E);

    // graph CSR build (counting sort by batch)
    k_gcount<<<(N + 127) / 128, 128, 0, stream>>>(batch, gcount, N);
    k_gscan<<<1, 128, 0, stream>>>(gcount, gptr);
    k_gscatter<<<(N + 127) / 128, 128, 0, stream>>>(batch, gptr, gfill, gnodes, N);

    // BN1 stats (run-amortized, contiguous chunks) + finalize
    const int STATS_BLOCKS = 2048;              // x4 waves = 8192 slots
    int per_slot = (E + STATS_BLOCKS * 4 - 1) / (STATS_BLOCKS * 4);
    k_stats<<<STATS_BLOCKS, 256, 0, stream>>>(Apk, (const uint2*)Cpk, snode, sidx1, bn1_sum, bn1_sq, E, per_slot);
    k_bn1fin<<<1, 256, 0, stream>>>(bn1_sum, bn1_sq, bn1_g, bn1_b, bn1_scale, bn1_shift, 1.0f / (float)E);

    // fused message + softmax aggregation (2 nodes per block)
    k_aggr<<<(N + 1) / 2, 128, 0, stream>>>(Apk, (const uint2*)Cpk, rowptr, sidx1, bn1_scale, bn1_shift, aggr_t, outbuf, N);

    // BN2 + residual/softplus + pool
    k_bn2stats<<<(N + 63) / 64, 128, 0, stream>>>(outbuf, bn2_sum, bn2_sq, N);
    k_bn2fin<<<1, 128, 0, stream>>>(bn2_sum, bn2_sq, bn2_g, bn2_b, bn2_scale, bn2_shift, 1.0f / (float)N);
    k_h2pool<16><<<128 * 16, 128, 0, stream>>>(outbuf, h, gptr, gnodes, bn2_scale, bn2_shift, pooled);

    // head
    k_head<<<128, 256, 0, stream>>>(pooled, gcount, l1_w, l1_b, out_w, out_b, (float*)d_out);
}

// Round 7
// 763.132 us; speedup vs baseline: 1.1222x; 1.1222x over previous
//
#include <hip/hip_runtime.h>
#include <hip/hip_bf16.h>

// CrystalHypergraphConv — MI355X implementation.
//
// Decomposition: z[e] = A[idx0[e]] + C[idx1[e]] where
//   A = h @ (lin_w[0:128]+lin_w[256:384]) + lin_b   [N,256]
//   C = connect_feats @ lin_w[128:256]              [NHE,256]
// C stored bf16-packed; lane l owns channels {2l,2l+1,128+2l,129+2l} ->
// per-edge gather = one uint2 (C) per lane.
//
// R6 -> R7: R6's gemm transpose was a double bug: stride-16 LDS writes
// (32-way bank conflict, 737k) + full K-unroll of float4 reads (VGPR 256,
// 294MB scratch spill). Fixed: row-major xs[r*K+k] (conflict-free writes),
// broadcast float4 reads per 4-k chunk (K%4==0 for all GEMMs), 4 scalar W
// loads per chunk, #pragma unroll 2 to cap registers. k_stats keeps the
// R6 run-amortized form (it left the top-5).

#define EPS_BN 1e-5f

__device__ __forceinline__ float softplus_fast(float x) {
    return fmaxf(x, 0.f) + __logf(1.f + __expf(-fabsf(x)));
}

__device__ __forceinline__ unsigned short f2bf(float f) {
    unsigned u = __float_as_uint(f);
    unsigned r = (u + 0x7fffu + ((u >> 16) & 1u)) >> 16;   // RNE
    return (unsigned short)r;
}
__device__ __forceinline__ float bflo(unsigned u) { return __uint_as_float(u << 16); }
__device__ __forceinline__ float bfhi(unsigned u) { return __uint_as_float(u & 0xffff0000u); }

// packed channel permutation for NCOL=256
__device__ __forceinline__ int perm256(int j) {
    return (j < 128) ? ((j >> 1) * 4 + (j & 1)) : (((j - 128) >> 1) * 4 + 2 + (j & 1));
}

// ---------------- dense GEMM: out[M,NCOL] = in[M,K] @ W[K,NCOL] + bias ----------------
// Row-major LDS (conflict-free fill); inner loop reads one broadcast float4
// per row per 4-k chunk (K % 4 == 0 for all instantiations).
// OMODE: 0 = natural f32, 1 = packed f32 (A), 2 = packed bf16 (C)
template<int K, int NCOL, int ROWS, int OMODE>
__global__ __launch_bounds__(NCOL) void gemm_rows(
    const float* __restrict__ in, const float* __restrict__ W,
    const float* __restrict__ bias, void* __restrict__ outv, int M)
{
    static_assert(K % 4 == 0, "K must be multiple of 4");
    __shared__ __align__(16) float xs[ROWS * K];
    const int j = threadIdx.x;
    const int r0 = blockIdx.x * ROWS;
    for (int i = j; i < ROWS * K; i += NCOL) {
        int r = i / K;
        int kk = i - r * K;
        int gi = r0 + r;
        xs[i] = (gi < M) ? in[(size_t)gi * K + kk] : 0.f;   // consecutive addrs -> no conflicts
    }
    __syncthreads();
    float b = bias ? bias[j] : 0.f;
    float acc[ROWS];
#pragma unroll
    for (int r = 0; r < ROWS; r++) acc[r] = b;
#pragma unroll 2
    for (int k4 = 0; k4 < K / 4; k4++) {
        const float* Wk = W + (size_t)(4 * k4) * NCOL + j;
        float w0 = Wk[0];
        float w1 = Wk[NCOL];
        float w2 = Wk[2 * NCOL];
        float w3 = Wk[3 * NCOL];
#pragma unroll
        for (int r = 0; r < ROWS; r++) {
            float4 xv = *(const float4*)(xs + r * K + 4 * k4);   // wave-broadcast b128
            acc[r] = fmaf(xv.x, w0, acc[r]);
            acc[r] = fmaf(xv.y, w1, acc[r]);
            acc[r] = fmaf(xv.z, w2, acc[r]);
            acc[r] = fmaf(xv.w, w3, acc[r]);
        }
    }
    const int pj = (OMODE && NCOL == 256) ? perm256(j) : j;
#pragma unroll
    for (int r = 0; r < ROWS; r++) {
        int gi = r0 + r;
        if (gi < M) {
            if (OMODE == 2) ((unsigned short*)outv)[(size_t)gi * NCOL + pj] = f2bf(acc[r]);
            else            ((float*)outv)[(size_t)gi * NCOL + pj] = acc[r];
        }
    }
}

// WA[k][j] = lin_w[k][j] + lin_w[k+256][j]
__global__ __launch_bounds__(256) void k_wa(const float* __restrict__ lw, float* __restrict__ WA) {
    int i = blockIdx.x * 256 + threadIdx.x;   // 0..32767
    WA[i] = lw[i] + lw[i + 256 * 256];
}

// ---------------- edge CSR build ----------------
__global__ __launch_bounds__(256) void k_hist(const int* __restrict__ idx0, int* __restrict__ hist, int E) {
    int e = blockIdx.x * 256 + threadIdx.x;
    if (e < E) atomicAdd(&hist[idx0[e]], 1);
}

__global__ __launch_bounds__(256) void k_scan1(const int* __restrict__ hist, int* __restrict__ incl,
                                               int* __restrict__ bsum, int N) {
    __shared__ int s[256];
    int i = blockIdx.x * 256 + threadIdx.x;
    int v = (i < N) ? hist[i] : 0;
    s[threadIdx.x] = v;
    __syncthreads();
    for (int ofs = 1; ofs < 256; ofs <<= 1) {
        int t = (threadIdx.x >= ofs) ? s[threadIdx.x - ofs] : 0;
        __syncthreads();
        s[threadIdx.x] += t;
        __syncthreads();
    }
    if (i < N) incl[i] = s[threadIdx.x];          // written at rowptr+1
    if (threadIdx.x == 255) bsum[blockIdx.x] = s[255];
}

__global__ __launch_bounds__(256) void k_scan2(const int* __restrict__ bsum, int* __restrict__ bofs, int nb) {
    __shared__ int s[256];
    int v = (threadIdx.x < nb) ? bsum[threadIdx.x] : 0;
    s[threadIdx.x] = v;
    __syncthreads();
    for (int ofs = 1; ofs < 256; ofs <<= 1) {
        int t = (threadIdx.x >= ofs) ? s[threadIdx.x - ofs] : 0;
        __syncthreads();
        s[threadIdx.x] += t;
        __syncthreads();
    }
    if (threadIdx.x < nb) bofs[threadIdx.x] = s[threadIdx.x] - v;  // exclusive
}

__global__ __launch_bounds__(256) void k_scan3(int* __restrict__ rowptr, const int* __restrict__ bofs, int N) {
    int i = blockIdx.x * 256 + threadIdx.x;
    if (i < N) rowptr[i + 1] += bofs[blockIdx.x];
    if (i == 0 && blockIdx.x == 0) rowptr[0] = 0;
}

__global__ __launch_bounds__(256) void k_scatter(const int* __restrict__ idx0, const int* __restrict__ idx1,
                                                 const int* __restrict__ rowptr, int* __restrict__ fill,
                                                 int* __restrict__ snode, int* __restrict__ sidx1, int E) {
    int e = blockIdx.x * 256 + threadIdx.x;
    if (e < E) {
        int n = idx0[e];
        int pos = rowptr[n] + atomicAdd(&fill[n], 1);
        snode[pos] = n;
        sidx1[pos] = idx1[e];
    }
}

// ---------------- graph CSR build (nodes sorted by batch) ----------------
__global__ __launch_bounds__(128) void k_gcount(const int* __restrict__ batch, int* __restrict__ gcount, int N) {
    int n = blockIdx.x * 128 + threadIdx.x;
    if (n < N) atomicAdd(&gcount[batch[n]], 1);
}

__global__ __launch_bounds__(128) void k_gscan(const int* __restrict__ gcount, int* __restrict__ gptr) {
    __shared__ int s[128];
    int t = threadIdx.x;
    s[t] = gcount[t];
    __syncthreads();
    for (int ofs = 1; ofs < 128; ofs <<= 1) {
        int v = (t >= ofs) ? s[t - ofs] : 0;
        __syncthreads();
        s[t] += v;
        __syncthreads();
    }
    gptr[t + 1] = s[t];
    if (t == 0) gptr[0] = 0;
}

__global__ __launch_bounds__(128) void k_gscatter(const int* __restrict__ batch, const int* __restrict__ gptr,
                                                  int* __restrict__ gfill, int* __restrict__ gnodes, int N) {
    int n = blockIdx.x * 128 + threadIdx.x;
    if (n < N) {
        int g = batch[n];
        int pos = gptr[g] + atomicAdd(&gfill[g], 1);
        gnodes[pos] = n;
    }
}

// ---------------- BN1 stats: run-amortized A, edge-parallel over contiguous chunks ----------------
__global__ __launch_bounds__(256) void k_stats(const float* __restrict__ Apk, const uint2* __restrict__ Cpk,
                                               const int* __restrict__ snode, const int* __restrict__ sidx1,
                                               float* __restrict__ gsum, float* __restrict__ gsq,
                                               int E, int per_slot) {
    __shared__ float4 lsm4[256], lsq4[256];
    const int t = threadIdx.x;
    const int s = t >> 6, l = t & 63;
    const float4* A4 = (const float4*)Apk;
    const long base = (long)(blockIdx.x * 4 + s) * per_slot;
    const int e0 = (int)min((long)E, base);
    const int e1 = (int)min((long)E, base + per_slot);
    float4 sm = {0.f, 0.f, 0.f, 0.f}, s2 = {0.f, 0.f, 0.f, 0.f};
    float4 csr = {0.f, 0.f, 0.f, 0.f};
    float4 a = {0.f, 0.f, 0.f, 0.f};
    int cur_n = -1, runk = 0;
    for (int e = e0; e < e1; e++) {
        int n = snode[e];        // wave-uniform
        int m = sidx1[e];
        if (n != cur_n) {        // wave-uniform branch
            if (runk) {
                float fk = (float)runk;
                sm.x += fmaf(fk, a.x, csr.x);
                sm.y += fmaf(fk, a.y, csr.y);
                sm.z += fmaf(fk, a.z, csr.z);
                sm.w += fmaf(fk, a.w, csr.w);
                float t0 = fmaf(fk, a.x, 2.f * csr.x); s2.x = fmaf(a.x, t0, s2.x);
                float t1 = fmaf(fk, a.y, 2.f * csr.y); s2.y = fmaf(a.y, t1, s2.y);
                float t2 = fmaf(fk, a.z, 2.f * csr.z); s2.z = fmaf(a.z, t2, s2.z);
                float t3 = fmaf(fk, a.w, 2.f * csr.w); s2.w = fmaf(a.w, t3, s2.w);
            }
            a = A4[(size_t)n * 64 + l];
            cur_n = n; runk = 0;
            csr.x = 0.f; csr.y = 0.f; csr.z = 0.f; csr.w = 0.f;
        }
        uint2 p = Cpk[(size_t)m * 64 + l];
        float c0 = bflo(p.x), c1 = bfhi(p.x), c2 = bflo(p.y), c3 = bfhi(p.y);
        csr.x += c0; csr.y += c1; csr.z += c2; csr.w += c3;
        s2.x = fmaf(c0, c0, s2.x);
        s2.y = fmaf(c1, c1, s2.y);
        s2.z = fmaf(c2, c2, s2.z);
        s2.w = fmaf(c3, c3, s2.w);
        runk++;
    }
    if (runk) {
        float fk = (float)runk;
        sm.x += fmaf(fk, a.x, csr.x);
        sm.y += fmaf(fk, a.y, csr.y);
        sm.z += fmaf(fk, a.z, csr.z);
        sm.w += fmaf(fk, a.w, csr.w);
        float t0 = fmaf(fk, a.x, 2.f * csr.x); s2.x = fmaf(a.x, t0, s2.x);
        float t1 = fmaf(fk, a.y, 2.f * csr.y); s2.y = fmaf(a.y, t1, s2.y);
        float t2 = fmaf(fk, a.z, 2.f * csr.z); s2.z = fmaf(a.z, t2, s2.z);
        float t3 = fmaf(fk, a.w, 2.f * csr.w); s2.w = fmaf(a.w, t3, s2.w);
    }
    lsm4[t] = sm;
    lsq4[t] = s2;
    __syncthreads();
    const float* fm = (const float*)lsm4;
    const float* fq = (const float*)lsq4;
    float vs = fm[t] + fm[256 + t] + fm[512 + t] + fm[768 + t];
    float vq = fq[t] + fq[256 + t] + fq[512 + t] + fq[768 + t];
    atomicAdd(&gsum[t], vs);   // packed channel index t
    atomicAdd(&gsq[t], vq);
}

// packed j -> original channel; writes packed scale/shift
__global__ __launch_bounds__(256) void k_bn1fin(const float* __restrict__ sum, const float* __restrict__ sq,
                                                const float* __restrict__ g, const float* __restrict__ b,
                                                float* __restrict__ scale, float* __restrict__ shift, float invE) {
    int j = threadIdx.x;  // packed index
    int l = j >> 2, k = j & 3;
    int ch = (k < 2) ? (2 * l + k) : (128 + 2 * l + (k - 2));
    float mu = sum[j] * invE;
    float var = sq[j] * invE - mu * mu;
    float sc = g[ch] * rsqrtf(var + EPS_BN);
    scale[j] = sc;
    shift[j] = fmaf(-mu, sc, b[ch]);
}

// ---------------- fused msg + segment softmax aggregation (2 waves/block, 1 node/wave) ----------------
__global__ __launch_bounds__(128) void k_aggr(const float* __restrict__ Apk, const uint2* __restrict__ Cpk,
                                              const int* __restrict__ rowptr, const int* __restrict__ sidx1,
                                              const float* __restrict__ scale_pk, const float* __restrict__ shift_pk,
                                              const float* __restrict__ tptr, float* __restrict__ out, int N) {
    const int n = blockIdx.x * 2 + (threadIdx.x >> 6);
    if (n >= N) return;
    const int l = threadIdx.x & 63;
    const float t = tptr[0];
    const float4 sc = ((const float4*)scale_pk)[l];
    const float4 sh = ((const float4*)shift_pk)[l];
    const float4 ap = ((const float4*)Apk)[(size_t)n * 64 + l];
    const float apf0 = fmaf(ap.x, sc.x, sh.x);
    const float apf1 = fmaf(ap.y, sc.y, sh.y);
    const float apc0 = fmaf(ap.z, sc.z, sh.z);
    const float apc1 = fmaf(ap.w, sc.w, sh.w);
    const int e0 = rowptr[n], e1 = rowptr[n + 1];
    float den0 = 0.f, num0 = 0.f, den1 = 0.f, num1 = 0.f;
    // 1-deep software prefetch: gather(e+1) in flight during compute(e)
    uint2 pnext = {0u, 0u};
    if (e0 < e1) pnext = Cpk[(size_t)sidx1[e0] * 64 + l];
    for (int e = e0; e < e1; e++) {
        uint2 p = pnext;
        if (e + 1 < e1) pnext = Cpk[(size_t)sidx1[e + 1] * 64 + l];
        float zf0 = fmaf(bflo(p.x), sc.x, apf0);
        float zf1 = fmaf(bfhi(p.x), sc.y, apf1);
        float zc0 = fmaf(bflo(p.y), sc.z, apc0);
        float zc1 = fmaf(bfhi(p.y), sc.w, apc1);
        float sig0 = __builtin_amdgcn_rcpf(1.f + __expf(-zf0));
        float sig1 = __builtin_amdgcn_rcpf(1.f + __expf(-zf1));
        float msg0 = sig0 * softplus_fast(zc0);
        float msg1 = sig1 * softplus_fast(zc1);
        float p0 = __expf(t * msg0);
        float p1 = __expf(t * msg1);
        den0 += p0; num0 = fmaf(msg0, p0, num0);
        den1 += p1; num1 = fmaf(msg1, p1, num1);
    }
    float2 o;
    o.x = (e1 > e0) ? num0 / den0 : 0.f;
    o.y = (e1 > e0) ? num1 / den1 : 0.f;
    ((float2*)out)[(size_t)n * 64 + l] = o;    // channels 2l, 2l+1 (natural order)
}

// ---------------- BN2 ----------------
__global__ __launch_bounds__(128) void k_bn2stats(const float* __restrict__ out, float* __restrict__ sum,
                                                  float* __restrict__ sq, int N) {
    const int c = threadIdx.x;  // 128
    const int n0 = blockIdx.x * 64;
    const int nend = min(n0 + 64, N);
    float sm = 0.f, s2 = 0.f;
    for (int n = n0; n < nend; n++) {
        float v = out[(size_t)n * 128 + c];
        sm += v;
        s2 = fmaf(v, v, s2);
    }
    atomicAdd(&sum[c], sm);
    atomicAdd(&sq[c], s2);
}

__global__ __launch_bounds__(128) void k_bn2fin(const float* __restrict__ sum, const float* __restrict__ sq,
                                                const float* __restrict__ g, const float* __restrict__ b,
                                                float* __restrict__ scale, float* __restrict__ shift, float invN) {
    int j = threadIdx.x;  // 128
    float mu = sum[j] * invN;
    float var = sq[j] * invN - mu * mu;
    float sc = g[j] * rsqrtf(var + EPS_BN);
    scale[j] = sc;
    shift[j] = fmaf(-mu, sc, b[j]);
}

// ---------------- residual+softplus + mean-pool (batch-CSR, register accum, no LDS) ----------------
template<int SPLIT>
__global__ __launch_bounds__(128) void k_h2pool(const float* __restrict__ out, const float* __restrict__ h,
                                                const int* __restrict__ gptr, const int* __restrict__ gnodes,
                                                const float* __restrict__ scale, const float* __restrict__ shift,
                                                float* __restrict__ pooled) {
    const int g = blockIdx.x & 127;
    const int sp = blockIdx.x >> 7;
    const int c = threadIdx.x;                 // 128
    const float sc = scale[c], sh = shift[c];
    const int i0 = gptr[g], i1 = gptr[g + 1];
    float acc = 0.f;
    for (int i = i0 + sp; i < i1; i += SPLIT) {
        int n = gnodes[i];
        float v = fmaf(out[(size_t)n * 128 + c], sc, sh) + h[(size_t)n * 128 + c];
        acc += softplus_fast(v);
    }
    if (acc != 0.f) atomicAdd(&pooled[g * 128 + c], acc);
}

// ---------------- head ----------------
__global__ __launch_bounds__(256) void k_head(const float* __restrict__ pooled, const int* __restrict__ gcount,
                                              const float* __restrict__ l1w, const float* __restrict__ l1b,
                                              const float* __restrict__ outw, const float* __restrict__ outb,
                                              float* __restrict__ dout) {
    __shared__ float p[128];
    __shared__ float red[256];
    const int g = blockIdx.x;
    const int j = threadIdx.x;  // 256
    if (j < 128) {
        float cnt = (float)max(gcount[g], 1);
        p[j] = pooled[g * 128 + j] / cnt;
    }
    __syncthreads();
    float acc = l1b[j];
    for (int k = 0; k < 128; k++) acc = fmaf(p[k], l1w[k * 256 + j], acc);
    red[j] = softplus_fast(acc) * outw[j];
    __syncthreads();
    for (int s = 128; s > 0; s >>= 1) {
        if (j < s) red[j] += red[j + s];
        __syncthreads();
    }
    if (j == 0) dout[g] = red[0] + outb[0];
}

// ---------------- launch ----------------
extern "C" void kernel_launch(void* const* d_in, const int* in_sizes, int n_in,
                              void* d_out, int out_size, void* d_ws, size_t ws_size,
                              hipStream_t stream) {
    const float* x        = (const float*)d_in[0];
    const float* hedge    = (const float*)d_in[1];
    const int*   iri      = (const int*)d_in[2];
    const int*   batch    = (const int*)d_in[3];
    const float* embed_w  = (const float*)d_in[5];
    const float* embed_b  = (const float*)d_in[6];
    const float* bembed_w = (const float*)d_in[7];
    const float* bembed_b = (const float*)d_in[8];
    const float* lin_w    = (const float*)d_in[9];
    const float* lin_b    = (const float*)d_in[10];
    const float* bn1_g    = (const float*)d_in[11];
    const float* bn1_b    = (const float*)d_in[12];
    const float* bn2_g    = (const float*)d_in[13];
    const float* bn2_b    = (const float*)d_in[14];
    const float* aggr_t   = (const float*)d_in[15];
    const float* l1_w     = (const float*)d_in[16];
    const float* l1_b     = (const float*)d_in[17];
    const float* out_w    = (const float*)d_in[18];
    const float* out_b    = (const float*)d_in[19];

    const int N   = in_sizes[0] / 92;
    const int NHE = in_sizes[1] / 40;
    const int E   = in_sizes[2] / 3;
    const int* idx0 = iri;
    const int* idx1 = iri + E;

    float* ws = (float*)d_ws;
    size_t off = 0;
    auto alloc = [&](size_t elems) -> float* {
        float* p = ws + off;
        off += (elems + 63) & ~(size_t)63;
        return p;
    };
    float* h      = alloc((size_t)N * 128);
    float* cf     = alloc((size_t)NHE * 128);
    float* Apk    = alloc((size_t)N * 256);        // packed f32
    float* Cpk    = alloc((size_t)NHE * 128);      // packed bf16 (NHE*256 u16)
    float* WA     = alloc(128 * 256);
    int*   rowptr = (int*)alloc((size_t)N + 1);
    int*   snode  = (int*)alloc((size_t)E);
    int*   sidx1  = (int*)alloc((size_t)E);
    int*   gptr   = (int*)alloc(129);
    int*   gnodes = (int*)alloc((size_t)N);
    int*   bsum   = (int*)alloc(256);
    int*   bofs   = (int*)alloc(256);
    float* bn1_scale = alloc(256);
    float* bn1_shift = alloc(256);
    float* bn2_scale = alloc(128);
    float* bn2_shift = alloc(128);
    float* outbuf = alloc((size_t)N * 128);
    // contiguous zero region
    float* zbase  = ws + off;
    int*   hist   = (int*)alloc((size_t)N);
    int*   fill   = (int*)alloc((size_t)N);
    int*   gfill  = (int*)alloc(128);
    float* bn1_sum = alloc(256);
    float* bn1_sq  = alloc(256);
    float* bn2_sum = alloc(128);
    float* bn2_sq  = alloc(128);
    float* pooled  = alloc(128 * 128);
    int*   gcount  = (int*)alloc(128);
    size_t zbytes = (size_t)((ws + off) - zbase) * sizeof(float);
    (void)ws_size;  // ~160MB; fit verified R1-R6

    hipMemsetAsync(zbase, 0, zbytes, stream);

    // dense precompute
    gemm_rows<92, 128, 16, 0><<<(N + 15) / 16, 128, 0, stream>>>(x, embed_w, embed_b, h, N);
    gemm_rows<40, 128, 16, 0><<<(NHE + 15) / 16, 128, 0, stream>>>(hedge, bembed_w, bembed_b, cf, NHE);
    k_wa<<<128, 256, 0, stream>>>(lin_w, WA);
    gemm_rows<128, 256, 16, 1><<<(N + 15) / 16, 256, 0, stream>>>(h, WA, lin_b, Apk, N);
    gemm_rows<128, 256, 16, 2><<<(NHE + 15) / 16, 256, 0, stream>>>(cf, lin_w + 128 * 256, nullptr, Cpk, NHE);

    // edge CSR build (counting sort by idx0)
    k_hist<<<(E + 255) / 256, 256, 0, stream>>>(idx0, hist, E);
    int nchunk = (N + 255) / 256;   // 196 <= 256
    k_scan1<<<nchunk, 256, 0, stream>>>(hist, rowptr + 1, bsum, N);
    k_scan2<<<1, 256, 0, stream>>>(bsum, bofs, nchunk);
    k_scan3<<<nchunk, 256, 0, stream>>>(rowptr, bofs, N);
    k_scatter<<<(E + 255) / 256, 256, 0, stream>>>(idx0, idx1, rowptr, fill, snode, sidx1, E);

    // graph CSR build (counting sort by batch)
    k_gcount<<<(N + 127) / 128, 128, 0, stream>>>(batch, gcount, N);
    k_gscan<<<1, 128, 0, stream>>>(gcount, gptr);
    k_gscatter<<<(N + 127) / 128, 128, 0, stream>>>(batch, gptr, gfill, gnodes, N);

    // BN1 stats (run-amortized, contiguous chunks) + finalize
    const int STATS_BLOCKS = 2048;              // x4 waves = 8192 slots
    int per_slot = (E + STATS_BLOCKS * 4 - 1) / (STATS_BLOCKS * 4);
    k_stats<<<STATS_BLOCKS, 256, 0, stream>>>(Apk, (const uint2*)Cpk, snode, sidx1, bn1_sum, bn1_sq, E, per_slot);
    k_bn1fin<<<1, 256, 0, stream>>>(bn1_sum, bn1_sq, bn1_g, bn1_b, bn1_scale, bn1_shift, 1.0f / (float)E);

    // fused message + softmax aggregation (2 nodes per block)
    k_aggr<<<(N + 1) / 2, 128, 0, stream>>>(Apk, (const uint2*)Cpk, rowptr, sidx1, bn1_scale, bn1_shift, aggr_t, outbuf, N);

    // BN2 + residual/softplus + pool
    k_bn2stats<<<(N + 63) / 64, 128, 0, stream>>>(outbuf, bn2_sum, bn2_sq, N);
    k_bn2fin<<<1, 128, 0, stream>>>(bn2_sum, bn2_sq, bn2_g, bn2_b, bn2_scale, bn2_shift, 1.0f / (float)N);
    k_h2pool<16><<<128 * 16, 128, 0, stream>>>(outbuf, h, gptr, gnodes, bn2_scale, bn2_shift, pooled);

    // head
    k_head<<<128, 256, 0, stream>>>(pooled, gcount, l1_w, l1_b, out_w, out_b, (float*)d_out);
}